// Round 6
// baseline (2844.753 us; speedup 1.0000x reference)
//
#include <hip/hip_runtime.h>

#define WAVE 64

// ---------------------------------------------------------------------------
// split pointcloud (B,N,6) -> xyz (B,N,3) + feats (B,N,3)
__global__ __launch_bounds__(256) void split_kernel(const float* __restrict__ pc,
    float* __restrict__ xyz, float* __restrict__ feats, int total) {
  int t = blockIdx.x * blockDim.x + threadIdx.x;
  if (t >= total) return;
  const float* p = pc + (size_t)t * 6;
  xyz[t * 3 + 0] = p[0]; xyz[t * 3 + 1] = p[1]; xyz[t * 3 + 2] = p[2];
  feats[t * 3 + 0] = p[3]; feats[t * 3 + 1] = p[4]; feats[t * 3 + 2] = p[5];
}

__global__ __launch_bounds__(256) void zero_kernel(float* __restrict__ p, int n) {
  int t = blockIdx.x * blockDim.x + threadIdx.x;
  if (t < n) p[t] = 0.f;
}

// ---------------------------------------------------------------------------
// Packed 2xf32 ops (VOP3P, gfx90a+). Per-element IEEE round-to-nearest —
// bit-identical to scalar v_add/v_mul, so FPS argmax decisions are unchanged.
// (No pk_fma: fused rounding would differ from the reference's mul+add.)
__device__ __forceinline__ float2 pk_add(float2 a, float2 b) {
  float2 r; asm("v_pk_add_f32 %0, %1, %2" : "=v"(r) : "v"(a), "v"(b)); return r;
}
__device__ __forceinline__ float2 pk_mul(float2 a, float2 b) {
  float2 r; asm("v_pk_mul_f32 %0, %1, %2" : "=v"(r) : "v"(a), "v"(b)); return r;
}

// ---------------------------------------------------------------------------
// Wave-wide reductions via DPP (VALU pipe only — no ds_swizzle LDS traffic).
// rocPRIM pattern: row_shr 1/2/4/8 + row_bcast15/31; full max lands in lane 63.
__device__ __forceinline__ float dpp_max_f32(float v) {
#define DPP_STEP_F(ctrl) { int t_ = __builtin_amdgcn_update_dpp( \
      __float_as_int(v), __float_as_int(v), ctrl, 0xf, 0xf, false); \
    v = fmaxf(v, __int_as_float(t_)); }
  DPP_STEP_F(0x111) DPP_STEP_F(0x112) DPP_STEP_F(0x114)
  DPP_STEP_F(0x118) DPP_STEP_F(0x142) DPP_STEP_F(0x143)
#undef DPP_STEP_F
  return v;  // valid in lane 63
}
__device__ __forceinline__ unsigned dpp_max_u32(unsigned v) {
#define DPP_STEP_U(ctrl) { unsigned t_ = (unsigned)__builtin_amdgcn_update_dpp( \
      (int)v, (int)v, ctrl, 0xf, 0xf, false); \
    v = (t_ > v) ? t_ : v; }
  DPP_STEP_U(0x111) DPP_STEP_U(0x112) DPP_STEP_U(0x114)
  DPP_STEP_U(0x118) DPP_STEP_U(0x142) DPP_STEP_U(0x143)
#undef DPP_STEP_U
  return v;  // valid in lane 63
}
__device__ __forceinline__ unsigned bcast63(unsigned v) {
  return (unsigned)__builtin_amdgcn_readlane((int)v, 63);
}

// ---------------------------------------------------------------------------
// FPS, layer 0: N=16384. 512 threads x 32 points held as 16 float2 pairs
// (x-of-pair, y-of-pair, z-of-pair) so the distance math runs on packed
// v_pk_add/v_pk_mul: 8 pk + 8 scalar instrs per PAIR vs 26 scalar (round-5
// main loop was ~42% of iter time). 160 live VGPRs < 256 cap at 2 waves/EU.
// Exact semantics: x+(-q) == x-q exactly; ((dx²+dy²)+dz²) add order kept;
// tie-break = smallest index (j ascending within thread; inverted-idx u32
// max across lanes/waves).
__global__ __launch_bounds__(512, 2) void fps_big_kernel(const float* __restrict__ xyz,
    float* __restrict__ new_xyz, int N, int S) {
  const int b = blockIdx.x;
  const int tid = threadIdx.x;
  const int lane = tid & 63;
  const int wv = tid >> 6;          // 8 waves
  const float* px = xyz + (size_t)b * N * 3;
  __shared__ unsigned long long s_key[3];
  float2 rx[16], ry[16], rz[16], mind[16];
#pragma unroll
  for (int p = 0; p < 16; ++p) {
    int i0 = tid + (2 * p) * 512;
    int i1 = tid + (2 * p + 1) * 512;
    rx[p] = make_float2(px[i0 * 3 + 0], px[i1 * 3 + 0]);
    ry[p] = make_float2(px[i0 * 3 + 1], px[i1 * 3 + 1]);
    rz[p] = make_float2(px[i0 * 3 + 2], px[i1 * 3 + 2]);
    asm volatile("" : "+v"(rx[p]), "+v"(ry[p]), "+v"(rz[p]));
    mind[p] = make_float2(1e10f, 1e10f);
  }
  (void)wv;
  if (tid < 3) s_key[tid] = 0ull;
  float qx = px[0], qy = px[1], qz = px[2];   // pick 0 is always index 0
  if (tid == 0) {
    float* o = new_xyz + (size_t)b * S * 3;
    o[0] = qx; o[1] = qy; o[2] = qz;
  }
  __syncthreads();
  for (unsigned it = 1; it < (unsigned)S; ++it) {
    float2 nqx = make_float2(-qx, -qx);
    float2 nqy = make_float2(-qy, -qy);
    float2 nqz = make_float2(-qz, -qz);
    float bestv = -1.f; unsigned besti = 0;
#pragma unroll
    for (int p = 0; p < 16; ++p) {
      float2 dx = pk_add(rx[p], nqx);          // x - q exactly
      float2 dy = pk_add(ry[p], nqy);
      float2 dz = pk_add(rz[p], nqz);
      float2 xx = pk_mul(dx, dx);
      float2 yy = pk_mul(dy, dy);
      float2 s1 = pk_add(xx, yy);
      float2 zz = pk_mul(dz, dz);
      float2 d  = pk_add(s1, zz);              // ((dx²+dy²)+dz²), _rn each step
      float m0 = fminf(mind[p].x, d.x);
      float m1 = fminf(mind[p].y, d.y);
      mind[p].x = m0; mind[p].y = m1;
      // j ascending => index ascending: strict > keeps first max on ties
      if (m0 > bestv) { bestv = m0; besti = (unsigned)(tid + (2 * p) * 512); }
      if (m1 > bestv) { bestv = m1; besti = (unsigned)(tid + (2 * p + 1) * 512); }
    }
    float wm = dpp_max_f32(bestv);
    unsigned wmb = bcast63(__float_as_uint(wm));
    unsigned cand = (__float_as_uint(bestv) == wmb) ? (0xFFFFFFFFu - besti) : 0u;
    unsigned winv = bcast63(dpp_max_u32(cand));
    if (lane == 0) atomicMax(&s_key[it % 3u], ((unsigned long long)wmb << 32) | winv);
    if (tid == 0) s_key[(it + 1) % 3u] = 0ull;
    __syncthreads();
    unsigned long long k = s_key[it % 3u];
    int last = (int)(0xFFFFFFFFu - (unsigned)k);
    const float* q = px + (size_t)last * 3;  // broadcast L2 load
    qx = q[0]; qy = q[1]; qz = q[2];
    if (tid == 0) {
      float* o = new_xyz + ((size_t)b * S + it) * 3;
      o[0] = qx; o[1] = qy; o[2] = qz;
    }
  }
}

// ---------------------------------------------------------------------------
// FPS, layers 1-3: T=N<=1024, one point per thread (regs) + coords mirrored
// in LDS for the winner lookup (no global reads in the loop).
__global__ void fps_small_kernel(const float* __restrict__ xyz,
    float* __restrict__ new_xyz, int N, int S) {
  const int b = blockIdx.x;
  const int tid = threadIdx.x;
  const int lane = tid & 63;
  const float* px = xyz + (size_t)b * N * 3;
  __shared__ float sx[1024], sy[1024], sz[1024];
  __shared__ unsigned long long s_key[3];
  float x = px[tid * 3 + 0], y = px[tid * 3 + 1], z = px[tid * 3 + 2];
  sx[tid] = x; sy[tid] = y; sz[tid] = z;
  if (tid < 3) s_key[tid] = 0ull;
  float mind = 1e10f;
  float qx = px[0], qy = px[1], qz = px[2];
  if (tid == 0) {
    float* o = new_xyz + (size_t)b * S * 3;
    o[0] = qx; o[1] = qy; o[2] = qz;
  }
  __syncthreads();
  for (unsigned it = 1; it < (unsigned)S; ++it) {
    float dx = __fsub_rn(x, qx);
    float dy = __fsub_rn(y, qy);
    float dz = __fsub_rn(z, qz);
    float d = __fadd_rn(__fadd_rn(__fmul_rn(dx, dx), __fmul_rn(dy, dy)), __fmul_rn(dz, dz));
    mind = fminf(mind, d);
    float wm = dpp_max_f32(mind);
    unsigned wmb = bcast63(__float_as_uint(wm));
    unsigned cand = (__float_as_uint(mind) == wmb) ? (0xFFFFFFFFu - (unsigned)tid) : 0u;
    unsigned winv = bcast63(dpp_max_u32(cand));
    if (lane == 0) atomicMax(&s_key[it % 3u], ((unsigned long long)wmb << 32) | winv);
    if (tid == 0) s_key[(it + 1) % 3u] = 0ull;
    __syncthreads();
    unsigned long long k = s_key[it % 3u];
    int last = (int)(0xFFFFFFFFu - (unsigned)k);
    qx = sx[last]; qy = sy[last]; qz = sz[last];   // LDS broadcast
    if (tid == 0) {
      float* o = new_xyz + ((size_t)b * S + it) * 3;
      o[0] = qx; o[1] = qy; o[2] = qz;
    }
  }
}

// ---------------------------------------------------------------------------
// Ball query: one wave per center; take the FIRST nsample indices (ascending)
// with d2 < r2 (== nsample smallest indices, matching top_k(-key)). Pad with
// the first hit (0 if no hits).
__global__ __launch_bounds__(256) void ballquery_kernel(const float* __restrict__ xyz,
    const float* __restrict__ centers, int* __restrict__ out_idx,
    int N, int S, int nsample, float r2) {
  int gw = (blockIdx.x * blockDim.x + threadIdx.x) >> 6;
  int lane = threadIdx.x & 63;
  int b = gw / S;
  int s = gw - b * S;
  const float* px = xyz + (size_t)b * N * 3;
  const float* cp = centers + ((size_t)b * S + s) * 3;
  float cx = cp[0], cy = cp[1], cz = cp[2];
  int* out = out_idx + ((size_t)b * S + s) * nsample;
  int cnt = 0;
  int firsti = 0;
  for (int base = 0; base < N; base += WAVE) {
    int i = base + lane;
    float dx = __fsub_rn(cx, px[i * 3 + 0]);
    float dy = __fsub_rn(cy, px[i * 3 + 1]);
    float dz = __fsub_rn(cz, px[i * 3 + 2]);
    float d = __fadd_rn(__fadd_rn(__fmul_rn(dx, dx), __fmul_rn(dy, dy)), __fmul_rn(dz, dz));
    bool hit = d < r2;
    unsigned long long m = __ballot(hit);
    if (hit) {
      int slot = cnt + __popcll(m & ((1ull << lane) - 1ull));
      if (slot < nsample) out[slot] = i;
    }
    if (cnt == 0 && m) firsti = base + __ffsll((unsigned long long)m) - 1;
    cnt += __popcll(m);
    if (cnt >= nsample) break;
  }
  for (int q = cnt + lane; q < nsample; q += WAVE) out[q] = firsti;
}

// ---------------------------------------------------------------------------
// Build X0 rows: [xyz[j]-center (3), feats[j] (ci)] for r=(b,s,k), c in [0,3+ci)
__global__ __launch_bounds__(256) void group_kernel(const float* __restrict__ xyz,
    const float* __restrict__ feats, const float* __restrict__ centers,
    const int* __restrict__ idx, float* __restrict__ X,
    int N, int S, int K, int ci, int R) {
  int t = blockIdx.x * blockDim.x + threadIdx.x;
  int C0 = ci + 3;
  int r = t / C0;
  if (r >= R) return;
  int c = t - r * C0;
  int g = r / K;          // b*S + s
  int b = g / S;
  int j = idx[r];
  float v;
  if (c < 3) v = __fsub_rn(xyz[((size_t)b * N + j) * 3 + c], centers[(size_t)g * 3 + c]);
  else       v = feats[((size_t)b * N + j) * ci + (c - 3)];
  X[(size_t)r * C0 + c] = v;
}

// ---------------------------------------------------------------------------
// Fused tiled f32 GEMM: Y(RxCo) = normReLU(A)(RxC) @ W(CxCo).
//  - if st_in != nullptr, A is normalized elementwise during LDS staging:
//      v = relu(gamma_in[c]*((a - mu[c])*rs[c]) + beta_in[c])
//    with mu/rs from st_in (prev sub-layer's sums; complete by stream order).
//  - per-channel sum/sumsq of Y accumulated into st_out (epilogue atomics)
//    -> replaces the separate stats pass (round-4 fusion).
// R % 64 == 0 always; C/Co guarded.
#define BM 64
#define BN 64
#define BK 16
__global__ __launch_bounds__(256) void mm_fused_kernel(const float* __restrict__ A,
    const float* __restrict__ W, float* __restrict__ Y,
    float* __restrict__ st_out, const float* __restrict__ st_in,
    const float* __restrict__ g_in, const float* __restrict__ b_in,
    int R, int C, int Co, float inv_n) {
  __shared__ float As[BK][BM + 4];
  __shared__ float Bs[BK][BN + 4];
  __shared__ float s_mu[260], s_rs[260], s_g[260], s_b[260];
  __shared__ float s_sum[BN], s_sq[BN];
  int r0 = blockIdx.x * BM;
  int n0 = blockIdx.y * BN;
  int tid = threadIdx.x;
  int tx = tid & 15, ty = tid >> 4;
  if (st_in) {
    for (int c = tid; c < C; c += 256) {
      float mu = st_in[c] * inv_n;
      float var = st_in[512 + c] * inv_n - mu * mu;
      s_mu[c] = mu; s_rs[c] = rsqrtf(var + 1e-5f);
      s_g[c] = g_in[c]; s_b[c] = b_in[c];
    }
  }
  if (tid < BN) { s_sum[tid] = 0.f; s_sq[tid] = 0.f; }
  __syncthreads();
  float acc[4][4] = {};
  for (int k0 = 0; k0 < C; k0 += BK) {
#pragma unroll
    for (int u = 0; u < 4; ++u) {
      int lin = tid + u * 256;
      int row = lin >> 4;
      int cc = lin & 15;
      int c = k0 + cc;
      float v = 0.f;
      if (c < C) {
        v = A[(size_t)(r0 + row) * C + c];
        if (st_in) {
          v = s_g[c] * ((v - s_mu[c]) * s_rs[c]) + s_b[c];
          v = v > 0.f ? v : 0.f;
        }
      }
      As[cc][row] = v;
    }
#pragma unroll
    for (int u = 0; u < 4; ++u) {
      int lin = tid + u * 256;
      int kk = lin >> 6;
      int n = lin & 63;
      int c = k0 + kk;
      Bs[kk][n] = (c < C && (n0 + n) < Co) ? W[(size_t)c * Co + n0 + n] : 0.f;
    }
    __syncthreads();
#pragma unroll
    for (int kk = 0; kk < BK; ++kk) {
      float a0[4], b0[4];
#pragma unroll
      for (int i = 0; i < 4; ++i) a0[i] = As[kk][ty * 4 + i];
#pragma unroll
      for (int jj = 0; jj < 4; ++jj) b0[jj] = Bs[kk][tx * 4 + jj];
#pragma unroll
      for (int i = 0; i < 4; ++i)
#pragma unroll
        for (int jj = 0; jj < 4; ++jj)
          acc[i][jj] = fmaf(a0[i], b0[jj], acc[i][jj]);
    }
    __syncthreads();
  }
#pragma unroll
  for (int i = 0; i < 4; ++i) {
    int r = r0 + ty * 4 + i;
#pragma unroll
    for (int jj = 0; jj < 4; ++jj) {
      int n = n0 + tx * 4 + jj;
      if (n < Co) Y[(size_t)r * Co + n] = acc[i][jj];
    }
  }
  // epilogue: per-column sum/sumsq of this block's tile -> LDS -> global
#pragma unroll
  for (int jj = 0; jj < 4; ++jj) {
    float cs = 0.f, cq = 0.f;
#pragma unroll
    for (int i = 0; i < 4; ++i) { float v = acc[i][jj]; cs += v; cq += v * v; }
    atomicAdd(&s_sum[tx * 4 + jj], cs);
    atomicAdd(&s_sq[tx * 4 + jj], cq);
  }
  __syncthreads();
  if (tid < BN) {
    int n = n0 + tid;
    if (n < Co) {
      atomicAdd(&st_out[n], s_sum[tid]);
      atomicAdd(&st_out[512 + n], s_sq[tid]);
    }
  }
}

// Last sub-layer: normalize+relu then max over the K samples of each group.
__global__ __launch_bounds__(256) void norm_relu_max_kernel(const float* __restrict__ Y,
    float* __restrict__ O, const float* __restrict__ st,
    const float* __restrict__ gamma, const float* __restrict__ beta,
    int G, int K, int Co, float inv_n) {
  int t = blockIdx.x * blockDim.x + threadIdx.x;
  if (t >= G * Co) return;
  int c = t & (Co - 1);
  int g = t / Co;
  float mu = st[c] * inv_n;
  float var = st[512 + c] * inv_n - mu * mu;
  float rs = rsqrtf(var + 1e-5f);
  float ga = gamma[c], be = beta[c];
  const float* yp = Y + (size_t)g * K * Co + c;
  float m = -1e30f;
  for (int k = 0; k < K; ++k) {
    float v = ga * ((yp[(size_t)k * Co] - mu) * rs) + be;
    m = fmaxf(m, v);
  }
  O[t] = m > 0.f ? m : 0.f;
}

// ---------------------------------------------------------------------------
extern "C" void kernel_launch(void* const* d_in, const int* in_sizes, int n_in,
                              void* d_out, int out_size, void* d_ws, size_t ws_size,
                              hipStream_t stream) {
  const float* pc = (const float*)d_in[0];
  float* out = (float*)d_out;
  char* wsb = (char*)d_ws;

  // ws layout: [0,1MB) ball idx; [1MB,+48KB) stats; [3MB,37MB) bufA; [37MB,104MB) bufB
  int* ballidx = (int*)wsb;
  float* stats = (float*)(wsb + ((size_t)1 << 20));
  float* bufA = (float*)(wsb + ((size_t)3 << 20));
  float* bufB = (float*)(wsb + ((size_t)37 << 20));

  const int B = 8;
  static const int Ns[4] = {16384, 1024, 256, 64};
  static const int Ss[4] = {1024, 256, 64, 16};
  static const int Ks[4] = {32, 32, 16, 16};
  static const double Rr[4] = {0.02, 0.04, 0.06, 0.08};
  static const int Ci[4] = {3, 64, 128, 256};
  static const int mlp[4][4] = {{6,32,32,64},{67,64,64,128},{131,128,128,256},{259,256,256,512}};
  static const size_t ox[5] = {0, 393216, 417792, 423936, 425472};
  static const size_t of[5] = {425856, 819072, 1343360, 1605504, 1736576};

  split_kernel<<<(B * 16384 + 255) / 256, 256, 0, stream>>>(pc, out + ox[0], out + of[0], B * 16384);
  zero_kernel<<<(12 * 1024 + 255) / 256, 256, 0, stream>>>(stats, 12 * 1024);

  for (int l = 0; l < 4; ++l) {
    const float* xyz = out + ox[l];
    const float* fts = out + of[l];
    float* nxyz = out + ox[l + 1];
    const int N = Ns[l], S = Ss[l], K = Ks[l], ci = Ci[l], C0 = ci + 3;
    const float r2 = (float)(Rr[l] * Rr[l]);

    if (l == 0) fps_big_kernel<<<B, 512, 0, stream>>>(xyz, nxyz, N, S);
    else        fps_small_kernel<<<B, N, 0, stream>>>(xyz, nxyz, N, S);

    ballquery_kernel<<<(B * S) / 4, 256, 0, stream>>>(xyz, nxyz, ballidx, N, S, K, r2);

    const int R = B * S * K;
    {
      int total = R * C0;
      group_kernel<<<(total + 255) / 256, 256, 0, stream>>>(xyz, fts, nxyz, ballidx, bufA,
                                                            N, S, K, ci, R);
    }

    const float inv_n = 1.0f / (float)R;
    float* X = bufA; float* Y = bufB;
    const float* prev_st = nullptr;
    const float* prev_g = nullptr;
    const float* prev_b = nullptr;
    for (int j = 0; j < 3; ++j) {
      const int cin = mlp[l][j], cout = mlp[l][j + 1];
      const float* Wt = (const float*)d_in[1 + (l * 3 + j) * 3 + 0];
      const float* Ga = (const float*)d_in[1 + (l * 3 + j) * 3 + 1];
      const float* Be = (const float*)d_in[1 + (l * 3 + j) * 3 + 2];
      float* st = stats + (size_t)(l * 3 + j) * 1024;
      dim3 grid(R / 64, (cout + 63) / 64);
      mm_fused_kernel<<<grid, 256, 0, stream>>>(X, Wt, Y, st, prev_st, prev_g, prev_b,
                                                R, cin, cout, inv_n);
      if (j < 2) {
        prev_st = st; prev_g = Ga; prev_b = Be;
        float* tswap = X; X = Y; Y = tswap;
      } else {
        int G = B * S;
        int tot = G * cout;
        norm_relu_max_kernel<<<(tot + 255) / 256, 256, 0, stream>>>(Y, out + of[l + 1], st, Ga, Be,
                                                                    G, K, cout, inv_n);
      }
    }
  }
}

// Round 7
// 2801.362 us; speedup vs baseline: 1.0155x; 1.0155x over previous
//
#include <hip/hip_runtime.h>

#define WAVE 64

// ---------------------------------------------------------------------------
// split pointcloud (B,N,6) -> xyz (B,N,3) + feats (B,N,3)
__global__ __launch_bounds__(256) void split_kernel(const float* __restrict__ pc,
    float* __restrict__ xyz, float* __restrict__ feats, int total) {
  int t = blockIdx.x * blockDim.x + threadIdx.x;
  if (t >= total) return;
  const float* p = pc + (size_t)t * 6;
  xyz[t * 3 + 0] = p[0]; xyz[t * 3 + 1] = p[1]; xyz[t * 3 + 2] = p[2];
  feats[t * 3 + 0] = p[3]; feats[t * 3 + 1] = p[4]; feats[t * 3 + 2] = p[5];
}

__global__ __launch_bounds__(256) void zero_kernel(float* __restrict__ p, int n) {
  int t = blockIdx.x * blockDim.x + threadIdx.x;
  if (t < n) p[t] = 0.f;
}

// ---------------------------------------------------------------------------
// Packed 2xf32 ops (VOP3P). Per-element IEEE round-to-nearest — bit-identical
// to scalar v_add/v_mul, so FPS argmax decisions are unchanged. No pk_fma
// (fused rounding would differ from the reference's mul+add).
__device__ __forceinline__ float2 pk_add(float2 a, float2 b) {
  float2 r; asm("v_pk_add_f32 %0, %1, %2" : "=v"(r) : "v"(a), "v"(b)); return r;
}
__device__ __forceinline__ float2 pk_mul(float2 a, float2 b) {
  float2 r; asm("v_pk_mul_f32 %0, %1, %2" : "=v"(r) : "v"(a), "v"(b)); return r;
}

// ---------------------------------------------------------------------------
// Wave-wide reductions via DPP (VALU pipe only — no ds_swizzle LDS traffic).
// rocPRIM pattern: row_shr 1/2/4/8 + row_bcast15/31; full max lands in lane 63.
__device__ __forceinline__ float dpp_max_f32(float v) {
#define DPP_STEP_F(ctrl) { int t_ = __builtin_amdgcn_update_dpp( \
      __float_as_int(v), __float_as_int(v), ctrl, 0xf, 0xf, false); \
    v = fmaxf(v, __int_as_float(t_)); }
  DPP_STEP_F(0x111) DPP_STEP_F(0x112) DPP_STEP_F(0x114)
  DPP_STEP_F(0x118) DPP_STEP_F(0x142) DPP_STEP_F(0x143)
#undef DPP_STEP_F
  return v;  // valid in lane 63
}
__device__ __forceinline__ unsigned dpp_max_u32(unsigned v) {
#define DPP_STEP_U(ctrl) { unsigned t_ = (unsigned)__builtin_amdgcn_update_dpp( \
      (int)v, (int)v, ctrl, 0xf, 0xf, false); \
    v = (t_ > v) ? t_ : v; }
  DPP_STEP_U(0x111) DPP_STEP_U(0x112) DPP_STEP_U(0x114)
  DPP_STEP_U(0x118) DPP_STEP_U(0x142) DPP_STEP_U(0x143)
#undef DPP_STEP_U
  return v;  // valid in lane 63
}
__device__ __forceinline__ unsigned bcast63(unsigned v) {
  return (unsigned)__builtin_amdgcn_readlane((int)v, 63);
}

// ---------------------------------------------------------------------------
// FPS, layer 0: N=16384, 1024 threads. Round-5/6 post-mortem: register-
// resident coords lose to the allocator (AGPR round-trips / remat) in every
// variant — both land ~4000 cyc/iter. This version puts xy in 128 KB of
// DYNAMIC LDS (deterministic ds_read_b64 stream, ~1024 cyc/iter on the LDS
// pipe, overlapped with ~1280 cyc VALU) and keeps only z[16]+mind[16] in
// registers (z pinned; even an AGPR fallback costs ~32 cyc/iter).
// Exact semantics: pk ops round per-element like scalar; (dx²+dy²)+dz² order
// kept; tie-break = smallest index via inverted-idx u32 max.
extern __shared__ char fps_dyn[];
__global__ __launch_bounds__(1024, 4) void fps_big_kernel(const float* __restrict__ xyz,
    float* __restrict__ new_xyz, int N, int S) {
  const int b = blockIdx.x;
  const int tid = threadIdx.x;
  const int lane = tid & 63;
  const float* px = xyz + (size_t)b * N * 3;
  float2* sxy = (float2*)fps_dyn;                                   // 16384 * 8B
  unsigned long long* s_key = (unsigned long long*)(fps_dyn + 131072);  // 3 slots
  float z[16], mind[16];
#pragma unroll
  for (int p = 0; p < 16; ++p) {
    int i = tid + p * 1024;
    sxy[i] = make_float2(px[i * 3 + 0], px[i * 3 + 1]);
    z[p] = px[i * 3 + 2];
    asm volatile("" : "+v"(z[p]));
    mind[p] = 1e10f;
  }
  if (tid < 3) s_key[tid] = 0ull;
  float qx = px[0], qy = px[1], qz = px[2];   // pick 0 is always index 0
  if (tid == 0) {
    float* o = new_xyz + (size_t)b * S * 3;
    o[0] = qx; o[1] = qy; o[2] = qz;
  }
  __syncthreads();
  for (unsigned it = 1; it < (unsigned)S; ++it) {
    float2 nq = make_float2(-qx, -qy);
    float bestv = -1.f; unsigned besti = 0;
#pragma unroll
    for (int p = 0; p < 16; ++p) {
      int i = tid + p * 1024;
      float2 xy = sxy[i];                      // ds_read_b64, stride-1 pattern
      float2 dxy = pk_add(xy, nq);             // (x-qx, y-qy) exactly
      float2 sq = pk_mul(dxy, dxy);            // (dx², dy²) each _rn
      float s1 = __fadd_rn(sq.x, sq.y);        // dx²+dy²
      float dz = __fsub_rn(z[p], qz);
      float d = __fadd_rn(s1, __fmul_rn(dz, dz));   // (dx²+dy²)+dz²
      float mo = fminf(mind[p], d);
      mind[p] = mo;
      // p ascending => index ascending within thread: keeps first max on ties
      if (mo > bestv) { bestv = mo; besti = (unsigned)i; }
    }
    float wm = dpp_max_f32(bestv);
    unsigned wmb = bcast63(__float_as_uint(wm));
    unsigned cand = (__float_as_uint(bestv) == wmb) ? (0xFFFFFFFFu - besti) : 0u;
    unsigned winv = bcast63(dpp_max_u32(cand));
    if (lane == 0) atomicMax(&s_key[it % 3u], ((unsigned long long)wmb << 32) | winv);
    if (tid == 0) s_key[(it + 1) % 3u] = 0ull;   // reset 2 barriers from last read
    __syncthreads();
    unsigned long long k = s_key[it % 3u];
    int last = (int)(0xFFFFFFFFu - (unsigned)k);
    float qzn = px[(size_t)last * 3 + 2];   // one global dword (L2 broadcast)
    float2 qn = sxy[last];                  // LDS broadcast, in flight concurrently
    qx = qn.x; qy = qn.y; qz = qzn;
    if (tid == 0) {
      float* o = new_xyz + ((size_t)b * S + it) * 3;
      o[0] = qx; o[1] = qy; o[2] = qz;
    }
  }
}

// ---------------------------------------------------------------------------
// FPS, layers 1-3: T=N<=1024, one point per thread (regs) + coords mirrored
// in LDS for the winner lookup (no global reads in the loop).
__global__ void fps_small_kernel(const float* __restrict__ xyz,
    float* __restrict__ new_xyz, int N, int S) {
  const int b = blockIdx.x;
  const int tid = threadIdx.x;
  const int lane = tid & 63;
  const float* px = xyz + (size_t)b * N * 3;
  __shared__ float sx[1024], sy[1024], sz[1024];
  __shared__ unsigned long long s_key[3];
  float x = px[tid * 3 + 0], y = px[tid * 3 + 1], z = px[tid * 3 + 2];
  sx[tid] = x; sy[tid] = y; sz[tid] = z;
  if (tid < 3) s_key[tid] = 0ull;
  float mind = 1e10f;
  float qx = px[0], qy = px[1], qz = px[2];
  if (tid == 0) {
    float* o = new_xyz + (size_t)b * S * 3;
    o[0] = qx; o[1] = qy; o[2] = qz;
  }
  __syncthreads();
  for (unsigned it = 1; it < (unsigned)S; ++it) {
    float dx = __fsub_rn(x, qx);
    float dy = __fsub_rn(y, qy);
    float dz = __fsub_rn(z, qz);
    float d = __fadd_rn(__fadd_rn(__fmul_rn(dx, dx), __fmul_rn(dy, dy)), __fmul_rn(dz, dz));
    mind = fminf(mind, d);
    float wm = dpp_max_f32(mind);
    unsigned wmb = bcast63(__float_as_uint(wm));
    unsigned cand = (__float_as_uint(mind) == wmb) ? (0xFFFFFFFFu - (unsigned)tid) : 0u;
    unsigned winv = bcast63(dpp_max_u32(cand));
    if (lane == 0) atomicMax(&s_key[it % 3u], ((unsigned long long)wmb << 32) | winv);
    if (tid == 0) s_key[(it + 1) % 3u] = 0ull;
    __syncthreads();
    unsigned long long k = s_key[it % 3u];
    int last = (int)(0xFFFFFFFFu - (unsigned)k);
    qx = sx[last]; qy = sy[last]; qz = sz[last];   // LDS broadcast
    if (tid == 0) {
      float* o = new_xyz + ((size_t)b * S + it) * 3;
      o[0] = qx; o[1] = qy; o[2] = qz;
    }
  }
}

// ---------------------------------------------------------------------------
// Ball query: one wave per center; take the FIRST nsample indices (ascending)
// with d2 < r2 (== nsample smallest indices, matching top_k(-key)). Pad with
// the first hit (0 if no hits).
__global__ __launch_bounds__(256) void ballquery_kernel(const float* __restrict__ xyz,
    const float* __restrict__ centers, int* __restrict__ out_idx,
    int N, int S, int nsample, float r2) {
  int gw = (blockIdx.x * blockDim.x + threadIdx.x) >> 6;
  int lane = threadIdx.x & 63;
  int b = gw / S;
  int s = gw - b * S;
  const float* px = xyz + (size_t)b * N * 3;
  const float* cp = centers + ((size_t)b * S + s) * 3;
  float cx = cp[0], cy = cp[1], cz = cp[2];
  int* out = out_idx + ((size_t)b * S + s) * nsample;
  int cnt = 0;
  int firsti = 0;
  for (int base = 0; base < N; base += WAVE) {
    int i = base + lane;
    float dx = __fsub_rn(cx, px[i * 3 + 0]);
    float dy = __fsub_rn(cy, px[i * 3 + 1]);
    float dz = __fsub_rn(cz, px[i * 3 + 2]);
    float d = __fadd_rn(__fadd_rn(__fmul_rn(dx, dx), __fmul_rn(dy, dy)), __fmul_rn(dz, dz));
    bool hit = d < r2;
    unsigned long long m = __ballot(hit);
    if (hit) {
      int slot = cnt + __popcll(m & ((1ull << lane) - 1ull));
      if (slot < nsample) out[slot] = i;
    }
    if (cnt == 0 && m) firsti = base + __ffsll((unsigned long long)m) - 1;
    cnt += __popcll(m);
    if (cnt >= nsample) break;
  }
  for (int q = cnt + lane; q < nsample; q += WAVE) out[q] = firsti;
}

// ---------------------------------------------------------------------------
// Build X0 rows: [xyz[j]-center (3), feats[j] (ci)] for r=(b,s,k), c in [0,3+ci)
__global__ __launch_bounds__(256) void group_kernel(const float* __restrict__ xyz,
    const float* __restrict__ feats, const float* __restrict__ centers,
    const int* __restrict__ idx, float* __restrict__ X,
    int N, int S, int K, int ci, int R) {
  int t = blockIdx.x * blockDim.x + threadIdx.x;
  int C0 = ci + 3;
  int r = t / C0;
  if (r >= R) return;
  int c = t - r * C0;
  int g = r / K;          // b*S + s
  int b = g / S;
  int j = idx[r];
  float v;
  if (c < 3) v = __fsub_rn(xyz[((size_t)b * N + j) * 3 + c], centers[(size_t)g * 3 + c]);
  else       v = feats[((size_t)b * N + j) * ci + (c - 3)];
  X[(size_t)r * C0 + c] = v;
}

// ---------------------------------------------------------------------------
// Fused tiled f32 GEMM: Y(RxCo) = normReLU(A)(RxC) @ W(CxCo).
//  - if st_in != nullptr, A is normalized elementwise during LDS staging:
//      v = relu(gamma_in[c]*((a - mu[c])*rs[c]) + beta_in[c])
//    with mu/rs from st_in (prev sub-layer's sums; complete by stream order).
//  - per-channel sum/sumsq of Y accumulated into st_out (epilogue atomics)
//    -> replaces the separate stats pass (round-4 fusion).
// R % 64 == 0 always; C/Co guarded.
#define BM 64
#define BN 64
#define BK 16
__global__ __launch_bounds__(256) void mm_fused_kernel(const float* __restrict__ A,
    const float* __restrict__ W, float* __restrict__ Y,
    float* __restrict__ st_out, const float* __restrict__ st_in,
    const float* __restrict__ g_in, const float* __restrict__ b_in,
    int R, int C, int Co, float inv_n) {
  __shared__ float As[BK][BM + 4];
  __shared__ float Bs[BK][BN + 4];
  __shared__ float s_mu[260], s_rs[260], s_g[260], s_b[260];
  __shared__ float s_sum[BN], s_sq[BN];
  int r0 = blockIdx.x * BM;
  int n0 = blockIdx.y * BN;
  int tid = threadIdx.x;
  int tx = tid & 15, ty = tid >> 4;
  if (st_in) {
    for (int c = tid; c < C; c += 256) {
      float mu = st_in[c] * inv_n;
      float var = st_in[512 + c] * inv_n - mu * mu;
      s_mu[c] = mu; s_rs[c] = rsqrtf(var + 1e-5f);
      s_g[c] = g_in[c]; s_b[c] = b_in[c];
    }
  }
  if (tid < BN) { s_sum[tid] = 0.f; s_sq[tid] = 0.f; }
  __syncthreads();
  float acc[4][4] = {};
  for (int k0 = 0; k0 < C; k0 += BK) {
#pragma unroll
    for (int u = 0; u < 4; ++u) {
      int lin = tid + u * 256;
      int row = lin >> 4;
      int cc = lin & 15;
      int c = k0 + cc;
      float v = 0.f;
      if (c < C) {
        v = A[(size_t)(r0 + row) * C + c];
        if (st_in) {
          v = s_g[c] * ((v - s_mu[c]) * s_rs[c]) + s_b[c];
          v = v > 0.f ? v : 0.f;
        }
      }
      As[cc][row] = v;
    }
#pragma unroll
    for (int u = 0; u < 4; ++u) {
      int lin = tid + u * 256;
      int kk = lin >> 6;
      int n = lin & 63;
      int c = k0 + kk;
      Bs[kk][n] = (c < C && (n0 + n) < Co) ? W[(size_t)c * Co + n0 + n] : 0.f;
    }
    __syncthreads();
#pragma unroll
    for (int kk = 0; kk < BK; ++kk) {
      float a0[4], b0[4];
#pragma unroll
      for (int i = 0; i < 4; ++i) a0[i] = As[kk][ty * 4 + i];
#pragma unroll
      for (int jj = 0; jj < 4; ++jj) b0[jj] = Bs[kk][tx * 4 + jj];
#pragma unroll
      for (int i = 0; i < 4; ++i)
#pragma unroll
        for (int jj = 0; jj < 4; ++jj)
          acc[i][jj] = fmaf(a0[i], b0[jj], acc[i][jj]);
    }
    __syncthreads();
  }
#pragma unroll
  for (int i = 0; i < 4; ++i) {
    int r = r0 + ty * 4 + i;
#pragma unroll
    for (int jj = 0; jj < 4; ++jj) {
      int n = n0 + tx * 4 + jj;
      if (n < Co) Y[(size_t)r * Co + n] = acc[i][jj];
    }
  }
  // epilogue: per-column sum/sumsq of this block's tile -> LDS -> global
#pragma unroll
  for (int jj = 0; jj < 4; ++jj) {
    float cs = 0.f, cq = 0.f;
#pragma unroll
    for (int i = 0; i < 4; ++i) { float v = acc[i][jj]; cs += v; cq += v * v; }
    atomicAdd(&s_sum[tx * 4 + jj], cs);
    atomicAdd(&s_sq[tx * 4 + jj], cq);
  }
  __syncthreads();
  if (tid < BN) {
    int n = n0 + tid;
    if (n < Co) {
      atomicAdd(&st_out[n], s_sum[tid]);
      atomicAdd(&st_out[512 + n], s_sq[tid]);
    }
  }
}

// Last sub-layer: normalize+relu then max over the K samples of each group.
__global__ __launch_bounds__(256) void norm_relu_max_kernel(const float* __restrict__ Y,
    float* __restrict__ O, const float* __restrict__ st,
    const float* __restrict__ gamma, const float* __restrict__ beta,
    int G, int K, int Co, float inv_n) {
  int t = blockIdx.x * blockDim.x + threadIdx.x;
  if (t >= G * Co) return;
  int c = t & (Co - 1);
  int g = t / Co;
  float mu = st[c] * inv_n;
  float var = st[512 + c] * inv_n - mu * mu;
  float rs = rsqrtf(var + 1e-5f);
  float ga = gamma[c], be = beta[c];
  const float* yp = Y + (size_t)g * K * Co + c;
  float m = -1e30f;
  for (int k = 0; k < K; ++k) {
    float v = ga * ((yp[(size_t)k * Co] - mu) * rs) + be;
    m = fmaxf(m, v);
  }
  O[t] = m > 0.f ? m : 0.f;
}

// ---------------------------------------------------------------------------
extern "C" void kernel_launch(void* const* d_in, const int* in_sizes, int n_in,
                              void* d_out, int out_size, void* d_ws, size_t ws_size,
                              hipStream_t stream) {
  const float* pc = (const float*)d_in[0];
  float* out = (float*)d_out;
  char* wsb = (char*)d_ws;

  // ws layout: [0,1MB) ball idx; [1MB,+48KB) stats; [3MB,37MB) bufA; [37MB,104MB) bufB
  int* ballidx = (int*)wsb;
  float* stats = (float*)(wsb + ((size_t)1 << 20));
  float* bufA = (float*)(wsb + ((size_t)3 << 20));
  float* bufB = (float*)(wsb + ((size_t)37 << 20));

  const int B = 8;
  static const int Ns[4] = {16384, 1024, 256, 64};
  static const int Ss[4] = {1024, 256, 64, 16};
  static const int Ks[4] = {32, 32, 16, 16};
  static const double Rr[4] = {0.02, 0.04, 0.06, 0.08};
  static const int Ci[4] = {3, 64, 128, 256};
  static const int mlp[4][4] = {{6,32,32,64},{67,64,64,128},{131,128,128,256},{259,256,256,512}};
  static const size_t ox[5] = {0, 393216, 417792, 423936, 425472};
  static const size_t of[5] = {425856, 819072, 1343360, 1605504, 1736576};

  // allow 128KB+32B dynamic LDS for fps_big (non-stream host call; idempotent,
  // safe under graph capture)
  const int FPS_DYN = 131072 + 32;
  hipFuncSetAttribute((const void*)fps_big_kernel,
                      hipFuncAttributeMaxDynamicSharedMemorySize, FPS_DYN);

  split_kernel<<<(B * 16384 + 255) / 256, 256, 0, stream>>>(pc, out + ox[0], out + of[0], B * 16384);
  zero_kernel<<<(12 * 1024 + 255) / 256, 256, 0, stream>>>(stats, 12 * 1024);

  for (int l = 0; l < 4; ++l) {
    const float* xyz = out + ox[l];
    const float* fts = out + of[l];
    float* nxyz = out + ox[l + 1];
    const int N = Ns[l], S = Ss[l], K = Ks[l], ci = Ci[l], C0 = ci + 3;
    const float r2 = (float)(Rr[l] * Rr[l]);

    if (l == 0) fps_big_kernel<<<B, 1024, FPS_DYN, stream>>>(xyz, nxyz, N, S);
    else        fps_small_kernel<<<B, N, 0, stream>>>(xyz, nxyz, N, S);

    ballquery_kernel<<<(B * S) / 4, 256, 0, stream>>>(xyz, nxyz, ballidx, N, S, K, r2);

    const int R = B * S * K;
    {
      int total = R * C0;
      group_kernel<<<(total + 255) / 256, 256, 0, stream>>>(xyz, fts, nxyz, ballidx, bufA,
                                                            N, S, K, ci, R);
    }

    const float inv_n = 1.0f / (float)R;
    float* X = bufA; float* Y = bufB;
    const float* prev_st = nullptr;
    const float* prev_g = nullptr;
    const float* prev_b = nullptr;
    for (int j = 0; j < 3; ++j) {
      const int cin = mlp[l][j], cout = mlp[l][j + 1];
      const float* Wt = (const float*)d_in[1 + (l * 3 + j) * 3 + 0];
      const float* Ga = (const float*)d_in[1 + (l * 3 + j) * 3 + 1];
      const float* Be = (const float*)d_in[1 + (l * 3 + j) * 3 + 2];
      float* st = stats + (size_t)(l * 3 + j) * 1024;
      dim3 grid(R / 64, (cout + 63) / 64);
      mm_fused_kernel<<<grid, 256, 0, stream>>>(X, Wt, Y, st, prev_st, prev_g, prev_b,
                                                R, cin, cout, inv_n);
      if (j < 2) {
        prev_st = st; prev_g = Ga; prev_b = Be;
        float* tswap = X; X = Y; Y = tswap;
      } else {
        int G = B * S;
        int tot = G * cout;
        norm_relu_max_kernel<<<(tot + 255) / 256, 256, 0, stream>>>(Y, out + of[l + 1], st, Ga, Be,
                                                                    G, K, cout, inv_n);
      }
    }
  }
}